// Round 1
// baseline (393.470 us; speedup 1.0000x reference)
//
#include <hip/hip_runtime.h>
#include <math.h>

#define T 512          // threads per block
#define APAD 1156      // 34*34 padded plane

// ---------------- Rot-matrix precompute (batch-independent) ----------------
__global__ void rot_prep_kernel(const float* __restrict__ qw, float* __restrict__ rot) {
    int g = threadIdx.x;
    if (g < 12) {
        float phi = qw[g * 3 + 0], theta = qw[g * 3 + 1], omega = qw[g * 3 + 2];
        float a = 0.5f * (phi + omega), d = 0.5f * (phi - omega);
        float st, ct; sincosf(0.5f * theta, &st, &ct);
        float sa, ca; sincosf(a, &sa, &ca);
        float sd, cd; sincosf(d, &sd, &cd);
        float* o = rot + g * 8;
        // U00 = e^{-ia} ct ; U01 = -e^{id} st ; U10 = e^{-id} st ; U11 = e^{ia} ct
        o[0] = ct * ca;  o[1] = -ct * sa;
        o[2] = -st * cd; o[3] = -st * sd;
        o[4] = st * cd;  o[5] = -st * sd;
        o[6] = ct * ca;  o[7] = ct * sa;
    }
}

// ---------------- generic 3x3 SAME conv + ReLU, LDS->LDS -------------------
template <int CIN, int COUT>
__device__ __forceinline__ void conv3x3_relu(const float* __restrict__ in,
                                             float* __restrict__ outp,
                                             const float* __restrict__ wg,
                                             const float* __restrict__ bg,
                                             int tid) {
    for (int p = tid; p < 1024; p += T) {
        const int y = p >> 5, xx = p & 31;
        const float* ib = in + y * 34 + xx;   // top-left of 3x3 window (padded)
        float acc[COUT];
#pragma unroll
        for (int oc = 0; oc < COUT; ++oc) acc[oc] = bg[oc];
#pragma unroll 2
        for (int ic = 0; ic < CIN; ++ic) {
            float v[9];
#pragma unroll
            for (int ky = 0; ky < 3; ++ky)
#pragma unroll
                for (int kx = 0; kx < 3; ++kx)
                    v[ky * 3 + kx] = ib[ic * APAD + ky * 34 + kx];
#pragma unroll
            for (int oc = 0; oc < COUT; ++oc) {
                const float* wp = wg + (oc * CIN + ic) * 9;   // block-uniform -> s_load
#pragma unroll
                for (int k = 0; k < 9; ++k)
                    acc[oc] = fmaf(wp[k], v[k], acc[oc]);
            }
        }
        float* ob = outp + (y + 1) * 34 + (xx + 1);
#pragma unroll
        for (int oc = 0; oc < COUT; ++oc)
            ob[oc * APAD] = fmaxf(acc[oc], 0.f);
    }
}

// ---------------- fully fused per-image kernel -----------------------------
__global__ __launch_bounds__(T) void fused_kernel(
    const float* __restrict__ x,
    const float* __restrict__ c1w, const float* __restrict__ c1b,
    const float* __restrict__ c2w, const float* __restrict__ c2b,
    const float* __restrict__ fcw, const float* __restrict__ fcb,
    const float* __restrict__ rot,
    const float* __restrict__ f2w, const float* __restrict__ f2b,
    const float* __restrict__ d1w, const float* __restrict__ d1b,
    const float* __restrict__ d2w, const float* __restrict__ d2b,
    float* __restrict__ out) {
    extern __shared__ float lds[];
    float* A  = lds;               // 16 * 1156 floats
    float* Bb = lds + 16 * APAD;   //  8 * 1156 floats
    float* S  = lds + 24 * APAD;   // small: ang[4], q[4], red[32]

    const int tid = threadIdx.x;
    const int b   = blockIdx.x;

    // zero all LDS planes (borders must be 0 for SAME padding)
    for (int i = tid; i < 24 * APAD; i += T) lds[i] = 0.f;
    __syncthreads();

    // ---- load x (3,32,32) into Bb interior ----
    const float* xb = x + b * 3072;
    for (int i = tid; i < 3072; i += T) {
        int c = i >> 10, p = i & 1023, y = p >> 5, xx = p & 31;
        Bb[c * APAD + (y + 1) * 34 + xx + 1] = xb[i];
    }
    __syncthreads();

    // ---- conv1 3->16 + relu ----
    conv3x3_relu<3, 16>(Bb, A, c1w, c1b, tid);
    __syncthreads();

    // ---- conv2 16->8 + relu ----
    conv3x3_relu<16, 8>(A, Bb, c2w, c2b, tid);
    __syncthreads();

    // ---- fc: ang[o] = sum_j h2[j] * fcw[o*8192+j] + fcb[o] ----
    {
        float part[4] = {0.f, 0.f, 0.f, 0.f};
        for (int j = tid; j < 8192; j += T) {
            int c = j >> 10, p = j & 1023, y = p >> 5, xx = p & 31;
            float v = Bb[c * APAD + (y + 1) * 34 + xx + 1];
#pragma unroll
            for (int o = 0; o < 4; ++o)
                part[o] = fmaf(v, fcw[o * 8192 + j], part[o]);
        }
#pragma unroll
        for (int off = 32; off; off >>= 1)
#pragma unroll
            for (int o = 0; o < 4; ++o)
                part[o] += __shfl_down(part[o], off);
        int wid = tid >> 6;
        if ((tid & 63) == 0) {
#pragma unroll
            for (int o = 0; o < 4; ++o) S[8 + wid * 4 + o] = part[o];
        }
        __syncthreads();
        if (tid == 0) {
#pragma unroll
            for (int o = 0; o < 4; ++o) {
                float s = fcb[o];
                for (int w = 0; w < T / 64; ++w) s += S[8 + w * 4 + o];
                S[o] = s;   // ang
            }
        }
        __syncthreads();
    }

    // ---- 4-qubit statevector sim on wave 0 (amplitude-per-lane, 16-group) ----
    if (tid < 64) {
        const int s = tid & 15;   // lanes 16-63 carry harmless replicas
        float re = (s == 0) ? 1.f : 0.f, im = 0.f;
        // RX embedding
#pragma unroll
        for (int w = 0; w < 4; ++w) {
            float a = S[w] * 0.5f;
            float sn, c; sincosf(a, &sn, &c);
            int stride = 1 << (3 - w);
            float pr = __shfl_xor(re, stride);
            float pi = __shfl_xor(im, stride);
            float nre = c * re + sn * pi;
            float nim = c * im - sn * pr;
            re = nre; im = nim;
        }
        // StronglyEntanglingLayers
#pragma unroll
        for (int l = 0; l < 3; ++l) {
#pragma unroll
            for (int w = 0; w < 4; ++w) {
                const float* U = rot + (l * 4 + w) * 8;   // uniform -> scalar loads
                int stride = 1 << (3 - w);
                bool bit = (s & stride) != 0;
                float pr = __shfl_xor(re, stride);
                float pi = __shfl_xor(im, stride);
                float cAr = bit ? U[6] : U[0], cAi = bit ? U[7] : U[1];
                float cBr = bit ? U[4] : U[2], cBi = bit ? U[5] : U[3];
                float nre = cAr * re - cAi * im + cBr * pr - cBi * pi;
                float nim = cAr * im + cAi * re + cBr * pi + cBi * pr;
                re = nre; im = nim;
            }
            const int r = (l % 3) + 1;
#pragma unroll
            for (int w = 0; w < 4; ++w) {
                int cs = 1 << (3 - w);
                int ts = 1 << (3 - ((w + r) & 3));
                float pr = __shfl_xor(re, ts);
                float pi = __shfl_xor(im, ts);
                if (s & cs) { re = pr; im = pi; }
            }
        }
        // PauliZ expvals
        float pprob = re * re + im * im;
        float ev[4];
#pragma unroll
        for (int w = 0; w < 4; ++w)
            ev[w] = (s & (1 << (3 - w))) ? -pprob : pprob;
#pragma unroll
        for (int m = 1; m <= 8; m <<= 1)
#pragma unroll
            for (int w = 0; w < 4; ++w)
                ev[w] += __shfl_xor(ev[w], m);
        if (tid == 0) {
#pragma unroll
            for (int w = 0; w < 4; ++w) S[4 + w] = ev[w];
        }
    }
    __syncthreads();

    // ---- fc2: h3[i] = sum_j q[j]*f2w[i*4+j] + f2b[i]  -> Bb interior ----
    {
        const float q0 = S[4], q1 = S[5], q2 = S[6], q3 = S[7];
        for (int i = tid; i < 8192; i += T) {
            int c = i >> 10, p = i & 1023, y = p >> 5, xx = p & 31;
            const float* wp = f2w + i * 4;
            float v = f2b[i];
            v = fmaf(q0, wp[0], v);
            v = fmaf(q1, wp[1], v);
            v = fmaf(q2, wp[2], v);
            v = fmaf(q3, wp[3], v);
            Bb[c * APAD + (y + 1) * 34 + xx + 1] = v;
        }
        __syncthreads();
    }

    // ---- dconv1 8->16 + relu ----
    conv3x3_relu<8, 16>(Bb, A, d1w, d1b, tid);
    __syncthreads();

    // ---- dconv2 16->3 + sigmoid -> global ----
    for (int p = tid; p < 1024; p += T) {
        const int y = p >> 5, xx = p & 31;
        const float* ib = A + y * 34 + xx;
        float acc[3];
#pragma unroll
        for (int oc = 0; oc < 3; ++oc) acc[oc] = d2b[oc];
#pragma unroll 2
        for (int ic = 0; ic < 16; ++ic) {
            float v[9];
#pragma unroll
            for (int ky = 0; ky < 3; ++ky)
#pragma unroll
                for (int kx = 0; kx < 3; ++kx)
                    v[ky * 3 + kx] = ib[ic * APAD + ky * 34 + kx];
#pragma unroll
            for (int oc = 0; oc < 3; ++oc) {
                const float* wp = d2w + (oc * 16 + ic) * 9;
#pragma unroll
                for (int k = 0; k < 9; ++k)
                    acc[oc] = fmaf(wp[k], v[k], acc[oc]);
            }
        }
        float* ob = out + b * 3072 + p;
#pragma unroll
        for (int oc = 0; oc < 3; ++oc)
            ob[oc * 1024] = 1.f / (1.f + expf(-acc[oc]));
    }
}

// ---------------- launch ----------------------------------------------------
extern "C" void kernel_launch(void* const* d_in, const int* in_sizes, int n_in,
                              void* d_out, int out_size, void* d_ws, size_t ws_size,
                              hipStream_t stream) {
    const float* x   = (const float*)d_in[0];
    const float* c1w = (const float*)d_in[1];
    const float* c1b = (const float*)d_in[2];
    const float* c2w = (const float*)d_in[3];
    const float* c2b = (const float*)d_in[4];
    const float* fcw = (const float*)d_in[5];
    const float* fcb = (const float*)d_in[6];
    const float* qw  = (const float*)d_in[7];
    const float* f2w = (const float*)d_in[8];
    const float* f2b = (const float*)d_in[9];
    const float* d1w = (const float*)d_in[10];
    const float* d1b = (const float*)d_in[11];
    const float* d2w = (const float*)d_in[12];
    const float* d2b = (const float*)d_in[13];
    float* out = (float*)d_out;
    float* rot = (float*)d_ws;   // 96 floats

    rot_prep_kernel<<<1, 64, 0, stream>>>(qw, rot);

    const size_t smem = (24 * APAD + 64) * sizeof(float);   // ~111.2 KB
    hipFuncSetAttribute((const void*)fused_kernel,
                        hipFuncAttributeMaxDynamicSharedMemorySize, (int)smem);
    fused_kernel<<<2048, T, smem, stream>>>(
        x, c1w, c1b, c2w, c2b, fcw, fcb, rot, f2w, f2b,
        d1w, d1b, d2w, d2b, out);
}

// Round 2
// 324.837 us; speedup vs baseline: 1.2113x; 1.2113x over previous
//
#include <hip/hip_runtime.h>
#include <math.h>

#define T 1024         // threads per block (16 waves -> 16 waves/CU at 1 block/CU)
#define APAD 1156      // 34*34 padded plane

// ---------------- Rot-matrix precompute (batch-independent) ----------------
__global__ void rot_prep_kernel(const float* __restrict__ qw, float* __restrict__ rot) {
    int g = threadIdx.x;
    if (g < 12) {
        float phi = qw[g * 3 + 0], theta = qw[g * 3 + 1], omega = qw[g * 3 + 2];
        float a = 0.5f * (phi + omega), d = 0.5f * (phi - omega);
        float st, ct; sincosf(0.5f * theta, &st, &ct);
        float sa, ca; sincosf(a, &sa, &ca);
        float sd, cd; sincosf(d, &sd, &cd);
        float* o = rot + g * 8;
        o[0] = ct * ca;  o[1] = -ct * sa;
        o[2] = -st * cd; o[3] = -st * sd;
        o[4] = st * cd;  o[5] = -st * sd;
        o[6] = ct * ca;  o[7] = ct * sa;
    }
}

// ---------------- generic 3x3 SAME conv + ReLU, LDS->LDS -------------------
template <int CIN, int COUT>
__device__ __forceinline__ void conv3x3_relu(const float* __restrict__ in,
                                             float* __restrict__ outp,
                                             const float* __restrict__ wg,
                                             const float* __restrict__ bg,
                                             int tid) {
    for (int p = tid; p < 1024; p += T) {
        const int y = p >> 5, xx = p & 31;
        const float* ib = in + y * 34 + xx;   // top-left of 3x3 window (padded)
        float acc[COUT];
#pragma unroll
        for (int oc = 0; oc < COUT; ++oc) acc[oc] = bg[oc];
#pragma unroll 2
        for (int ic = 0; ic < CIN; ++ic) {
            float v[9];
#pragma unroll
            for (int ky = 0; ky < 3; ++ky)
#pragma unroll
                for (int kx = 0; kx < 3; ++kx)
                    v[ky * 3 + kx] = ib[ic * APAD + ky * 34 + kx];
#pragma unroll
            for (int oc = 0; oc < COUT; ++oc) {
                const float* wp = wg + (oc * CIN + ic) * 9;   // block-uniform -> s_load
#pragma unroll
                for (int k = 0; k < 9; ++k)
                    acc[oc] = fmaf(wp[k], v[k], acc[oc]);
            }
        }
        float* ob = outp + (y + 1) * 34 + (xx + 1);
#pragma unroll
        for (int oc = 0; oc < COUT; ++oc)
            ob[oc * APAD] = fmaxf(acc[oc], 0.f);
    }
}

// ---------------- fully fused per-image kernel -----------------------------
__global__ __launch_bounds__(T) void fused_kernel(
    const float* __restrict__ x,
    const float* __restrict__ c1w, const float* __restrict__ c1b,
    const float* __restrict__ c2w, const float* __restrict__ c2b,
    const float* __restrict__ fcw, const float* __restrict__ fcb,
    const float* __restrict__ rot,
    const float* __restrict__ f2w, const float* __restrict__ f2b,
    const float* __restrict__ d1w, const float* __restrict__ d1b,
    const float* __restrict__ d2w, const float* __restrict__ d2b,
    float* __restrict__ out) {
    extern __shared__ float lds[];
    float* A  = lds;               // 16 * 1156 floats
    float* Bb = lds + 16 * APAD;   //  8 * 1156 floats
    float* S  = lds + 24 * APAD;   // small: ang[4], q[4], red[16*4]

    const int tid = threadIdx.x;
    const int b   = blockIdx.x;

    // zero all LDS planes (borders must be 0 for SAME padding)
    for (int i = tid; i < 24 * APAD; i += T) lds[i] = 0.f;
    __syncthreads();

    // ---- load x (3,32,32) into Bb interior ----
    const float* xb = x + b * 3072;
    for (int i = tid; i < 3072; i += T) {
        int c = i >> 10, p = i & 1023, y = p >> 5, xx = p & 31;
        Bb[c * APAD + (y + 1) * 34 + xx + 1] = xb[i];
    }
    __syncthreads();

    // ---- conv1 3->16 + relu ----
    conv3x3_relu<3, 16>(Bb, A, c1w, c1b, tid);
    __syncthreads();

    // ---- conv2 16->8 + relu ----
    conv3x3_relu<16, 8>(A, Bb, c2w, c2b, tid);
    __syncthreads();

    // ---- fc: ang[o] = sum_j h2[j] * fcw[o*8192+j] + fcb[o] ----
    {
        float part[4] = {0.f, 0.f, 0.f, 0.f};
        for (int j = tid; j < 8192; j += T) {
            int c = j >> 10, p = j & 1023, y = p >> 5, xx = p & 31;
            float v = Bb[c * APAD + (y + 1) * 34 + xx + 1];
#pragma unroll
            for (int o = 0; o < 4; ++o)
                part[o] = fmaf(v, fcw[o * 8192 + j], part[o]);
        }
#pragma unroll
        for (int off = 32; off; off >>= 1)
#pragma unroll
            for (int o = 0; o < 4; ++o)
                part[o] += __shfl_down(part[o], off);
        int wid = tid >> 6;
        if ((tid & 63) == 0) {
#pragma unroll
            for (int o = 0; o < 4; ++o) S[8 + wid * 4 + o] = part[o];
        }
        __syncthreads();
        if (tid == 0) {
#pragma unroll
            for (int o = 0; o < 4; ++o) {
                float s = fcb[o];
                for (int w = 0; w < T / 64; ++w) s += S[8 + w * 4 + o];
                S[o] = s;   // ang
            }
        }
        __syncthreads();
    }

    // ---- 4-qubit statevector sim on wave 0 (amplitude-per-lane, 16-group) ----
    if (tid < 64) {
        const int s = tid & 15;   // lanes 16-63 carry harmless replicas
        float re = (s == 0) ? 1.f : 0.f, im = 0.f;
        // RX embedding
#pragma unroll
        for (int w = 0; w < 4; ++w) {
            float a = S[w] * 0.5f;
            float sn, c; sincosf(a, &sn, &c);
            int stride = 1 << (3 - w);
            float pr = __shfl_xor(re, stride);
            float pi = __shfl_xor(im, stride);
            float nre = c * re + sn * pi;
            float nim = c * im - sn * pr;
            re = nre; im = nim;
        }
        // StronglyEntanglingLayers
#pragma unroll
        for (int l = 0; l < 3; ++l) {
#pragma unroll
            for (int w = 0; w < 4; ++w) {
                const float* U = rot + (l * 4 + w) * 8;   // uniform -> scalar loads
                int stride = 1 << (3 - w);
                bool bit = (s & stride) != 0;
                float pr = __shfl_xor(re, stride);
                float pi = __shfl_xor(im, stride);
                float cAr = bit ? U[6] : U[0], cAi = bit ? U[7] : U[1];
                float cBr = bit ? U[4] : U[2], cBi = bit ? U[5] : U[3];
                float nre = cAr * re - cAi * im + cBr * pr - cBi * pi;
                float nim = cAr * im + cAi * re + cBr * pi + cBi * pr;
                re = nre; im = nim;
            }
            const int r = (l % 3) + 1;
#pragma unroll
            for (int w = 0; w < 4; ++w) {
                int cs = 1 << (3 - w);
                int ts = 1 << (3 - ((w + r) & 3));
                float pr = __shfl_xor(re, ts);
                float pi = __shfl_xor(im, ts);
                if (s & cs) { re = pr; im = pi; }
            }
        }
        // PauliZ expvals
        float pprob = re * re + im * im;
        float ev[4];
#pragma unroll
        for (int w = 0; w < 4; ++w)
            ev[w] = (s & (1 << (3 - w))) ? -pprob : pprob;
#pragma unroll
        for (int m = 1; m <= 8; m <<= 1)
#pragma unroll
            for (int w = 0; w < 4; ++w)
                ev[w] += __shfl_xor(ev[w], m);
        if (tid == 0) {
#pragma unroll
            for (int w = 0; w < 4; ++w) S[4 + w] = ev[w];
        }
    }
    __syncthreads();

    // ---- fc2: h3[i] = sum_j q[j]*f2w[i*4+j] + f2b[i]  -> Bb interior ----
    {
        const float q0 = S[4], q1 = S[5], q2 = S[6], q3 = S[7];
        for (int i = tid; i < 8192; i += T) {
            int c = i >> 10, p = i & 1023, y = p >> 5, xx = p & 31;
            const float* wp = f2w + i * 4;
            float v = f2b[i];
            v = fmaf(q0, wp[0], v);
            v = fmaf(q1, wp[1], v);
            v = fmaf(q2, wp[2], v);
            v = fmaf(q3, wp[3], v);
            Bb[c * APAD + (y + 1) * 34 + xx + 1] = v;
        }
        __syncthreads();
    }

    // ---- dconv1 8->16 + relu ----
    conv3x3_relu<8, 16>(Bb, A, d1w, d1b, tid);
    __syncthreads();

    // ---- dconv2 16->3 + sigmoid -> global ----
    for (int p = tid; p < 1024; p += T) {
        const int y = p >> 5, xx = p & 31;
        const float* ib = A + y * 34 + xx;
        float acc[3];
#pragma unroll
        for (int oc = 0; oc < 3; ++oc) acc[oc] = d2b[oc];
#pragma unroll 2
        for (int ic = 0; ic < 16; ++ic) {
            float v[9];
#pragma unroll
            for (int ky = 0; ky < 3; ++ky)
#pragma unroll
                for (int kx = 0; kx < 3; ++kx)
                    v[ky * 3 + kx] = ib[ic * APAD + ky * 34 + kx];
#pragma unroll
            for (int oc = 0; oc < 3; ++oc) {
                const float* wp = d2w + (oc * 16 + ic) * 9;
#pragma unroll
                for (int k = 0; k < 9; ++k)
                    acc[oc] = fmaf(wp[k], v[k], acc[oc]);
            }
        }
        float* ob = out + b * 3072 + p;
#pragma unroll
        for (int oc = 0; oc < 3; ++oc)
            ob[oc * 1024] = 1.f / (1.f + expf(-acc[oc]));
    }
}

// ---------------- launch ----------------------------------------------------
extern "C" void kernel_launch(void* const* d_in, const int* in_sizes, int n_in,
                              void* d_out, int out_size, void* d_ws, size_t ws_size,
                              hipStream_t stream) {
    const float* x   = (const float*)d_in[0];
    const float* c1w = (const float*)d_in[1];
    const float* c1b = (const float*)d_in[2];
    const float* c2w = (const float*)d_in[3];
    const float* c2b = (const float*)d_in[4];
    const float* fcw = (const float*)d_in[5];
    const float* fcb = (const float*)d_in[6];
    const float* qw  = (const float*)d_in[7];
    const float* f2w = (const float*)d_in[8];
    const float* f2b = (const float*)d_in[9];
    const float* d1w = (const float*)d_in[10];
    const float* d1b = (const float*)d_in[11];
    const float* d2w = (const float*)d_in[12];
    const float* d2b = (const float*)d_in[13];
    float* out = (float*)d_out;
    float* rot = (float*)d_ws;   // 96 floats

    rot_prep_kernel<<<1, 64, 0, stream>>>(qw, rot);

    const size_t smem = (24 * APAD + 128) * sizeof(float);   // ~111.4 KB
    hipFuncSetAttribute((const void*)fused_kernel,
                        hipFuncAttributeMaxDynamicSharedMemorySize, (int)smem);
    fused_kernel<<<2048, T, smem, stream>>>(
        x, c1w, c1b, c2w, c2b, fcw, fcb, rot, f2w, f2b,
        d1w, d1b, d2w, d2b, out);
}